// Round 4
// baseline (746.049 us; speedup 1.0000x reference)
//
#include <hip/hip_runtime.h>

typedef __attribute__((ext_vector_type(8))) short short8;
typedef __attribute__((ext_vector_type(4))) float f32x4;
typedef unsigned short u16;
typedef unsigned int u32;

#define DEVI __device__ __forceinline__

// round-to-nearest-even f32 -> bf16 bits
DEVI u16 f2bf(float f) {
    union { float f; u32 u; } v; v.f = f;
    u32 r = v.u + 0x7FFFu + ((v.u >> 16) & 1u);
    return (u16)(r >> 16);
}

// ---------------- f32 -> bf16 bulk convert (vec4) ----------------
__global__ void cvt_bf16_kernel(const float* __restrict__ in, u16* __restrict__ out, int n4) {
    int i = blockIdx.x * blockDim.x + threadIdx.x;
    int stride = gridDim.x * blockDim.x;
    for (; i < n4; i += stride) {
        float4 v = reinterpret_cast<const float4*>(in)[i];
        ushort4 o;
        o.x = f2bf(v.x); o.y = f2bf(v.y); o.z = f2bf(v.z); o.w = f2bf(v.w);
        reinterpret_cast<ushort4*>(out)[i] = o;
    }
}

// ---------------- embed + pos + leaky1 -> bf16 A ----------------
// 256 blocks x 64 threads; each block handles one b (fixed) x 64 h values.
__global__ __launch_bounds__(64)
void embed_leaky_kernel(const int* __restrict__ x, const float* __restrict__ emb,
                        const float* __restrict__ pos, const float* __restrict__ beta,
                        u16* __restrict__ Aout) {
    __shared__ int xs[128];
    int gtid = blockIdx.x * 64 + threadIdx.x;
    int b = gtid >> 9;      // constant per block
    int h = gtid & 511;
    for (int i = threadIdx.x; i < 128; i += 64) xs[i] = x[i * 32 + b];
    __syncthreads();
    float be = beta[h];
    float mem = 0.f;
    for (int t0 = 0; t0 < 128; t0 += 8) {
        float e[8];
#pragma unroll
        for (int j = 0; j < 8; ++j)
            e[j] = emb[(size_t)xs[t0 + j] * 512 + h] + pos[(t0 + j) * 512 + h];
#pragma unroll
        for (int j = 0; j < 8; ++j) {
            mem = be * mem + e[j];
            Aout[(size_t)((t0 + j) * 32 + b) * 512 + h] = f2bf(mem);
        }
    }
}

// ---------------- leaky over f32 input -> bf16 A ----------------
__global__ __launch_bounds__(64)
void leaky_bf16_kernel(const float* __restrict__ in, const float* __restrict__ beta,
                       u16* __restrict__ Aout) {
    int gtid = blockIdx.x * 64 + threadIdx.x;
    int b = gtid >> 9;
    int h = gtid & 511;
    float be = beta[h];
    float mem = 0.f;
    for (int t0 = 0; t0 < 128; t0 += 8) {
        float v[8];
#pragma unroll
        for (int j = 0; j < 8; ++j)
            v[j] = in[(size_t)((t0 + j) * 32 + b) * 512 + h];
#pragma unroll
        for (int j = 0; j < 8; ++j) {
            mem = be * mem + v[j];
            Aout[(size_t)((t0 + j) * 32 + b) * 512 + h] = f2bf(mem);
        }
    }
}

// ---------------- bf16 GEMM, C = A * B^T + bias (opt ReLU) ----------------
// A: [M, K] bf16 row-major (M % 128 == 0)
// B: [Npad, K] bf16 row-major (rows are output columns; Npad % 128 == 0)
// C: [M, N] f32
// LDS layout per tile: [4 k-pages][128 rows][16B] -> conflict-free frag reads.
// Triple-buffered staging, counted vmcnt(4), raw s_barrier per K-iter.
// Epilogue: LDS-transposed, wave-contiguous 256B caching stores.
// VOCAB: col guard to N, bijective XCD-chunked bn-major swizzle.
template<bool RELU, bool VOCAB>
__global__ __launch_bounds__(256)
void gemm_bt_128(const u16* __restrict__ A, const u16* __restrict__ B,
                 const float* __restrict__ bias, float* __restrict__ C,
                 int M, int N, int K, int tiles_m, int tiles_n) {
    __shared__ alignas(16) char smem[3 * 16384];   // 3 bufs x (A 8K + B 8K)
    float* Ep = (float*)smem;                      // 32x132 f32 epilogue staging (aliases buf0/1)

    const int tid = threadIdx.x;
    int bm, bn;
    if (VOCAB) {
        // bijective XCD-chunked remap, bn-major (bm fastest): B-panel reused
        // across 32 bm per XCD (L2-resident); A (4MB) L2-resident per XCD.
        int nwg = tiles_m * tiles_n;
        int q = nwg >> 3, r = nwg & 7;
        int xcd = blockIdx.x & 7, idx = blockIdx.x >> 3;
        int wg = (xcd < r ? xcd * (q + 1) : r * (q + 1) + (xcd - r) * q) + idx;
        bn = wg / tiles_m;
        bm = wg % tiles_m;
    } else {
        bm = blockIdx.x / tiles_n;
        bn = blockIdx.x % tiles_n;
    }
    const int wv = tid >> 6;
    const int lane = tid & 63;
    const int wr = wv >> 1, wc = wv & 1;
    const int lrow = lane & 15;   // fragment row (A) / col (B) / C col
    const int kg = lane >> 4;     // k-page (8 bf16 each)

    f32x4 acc[4][4];
#pragma unroll
    for (int i = 0; i < 4; ++i)
#pragma unroll
        for (int j = 0; j < 4; ++j) acc[i][j] = (f32x4){0.f, 0.f, 0.f, 0.f};

    const size_t rowb = (size_t)K * 2;  // bytes per row
    const char* Ab = (const char*)A + (size_t)(bm * 128) * rowb;
    const char* Bb = (const char*)B + (size_t)(bn * 128) * rowb;

    // bias per lane-fragment-col, loaded up front
    float bv[4];
#pragma unroll
    for (int ni = 0; ni < 4; ++ni) {
        int col = bn * 128 + wc * 64 + ni * 16 + lrow;
        bv[ni] = (!VOCAB || col < N) ? bias[col] : 0.f;
    }

    // stage tile kk (byte col offset kk*2) into buffer bufi.
    // LDS slot s (0..511) = page(s>>7)*128 + row(s&127); global src permuted to match.
    auto STAGE = [&](int bufi, int kk) {
        char* dstA = smem + bufi * 16384;
        char* dstB = dstA + 8192;
        int k2 = kk << 1;
#pragma unroll
        for (int r = 0; r < 2; ++r) {
            int slot = r * 256 + tid;
            int row = slot & 127;
            int pg = slot >> 7;
            size_t goff = (size_t)row * rowb + k2 + pg * 16;
            __builtin_amdgcn_global_load_lds(
                (const __attribute__((address_space(1))) void*)(Ab + goff),
                (__attribute__((address_space(3))) void*)(dstA + slot * 16), 16, 0, 0);
            __builtin_amdgcn_global_load_lds(
                (const __attribute__((address_space(1))) void*)(Bb + goff),
                (__attribute__((address_space(3))) void*)(dstB + slot * 16), 16, 0, 0);
        }
    };

    const int nt = K >> 5;   // 32-wide K tiles (nt >= 2 assumed)

    // prologue: stage T0, T1; wait T0 landed (4 loads of T1 may fly)
    STAGE(0, 0);
    STAGE(1, 32);
    asm volatile("s_waitcnt vmcnt(4)" ::: "memory");
    __builtin_amdgcn_s_barrier();
    __builtin_amdgcn_sched_barrier(0);

    for (int t = 0; t < nt; ++t) {
        const int cur = t % 3;
        const u16* As = (const u16*)(smem + cur * 16384);
        const u16* Bs = (const u16*)(smem + cur * 16384 + 8192);
        short8 a[4], b[4];
#pragma unroll
        for (int mi = 0; mi < 4; ++mi)
            a[mi] = *(const short8*)&As[kg * 1024 + (wr * 64 + mi * 16 + lrow) * 8];
#pragma unroll
        for (int ni = 0; ni < 4; ++ni)
            b[ni] = *(const short8*)&Bs[kg * 1024 + (wc * 64 + ni * 16 + lrow) * 8];

        if (t + 2 < nt) STAGE((t + 2) % 3, (t + 2) * 32);

#pragma unroll
        for (int mi = 0; mi < 4; ++mi)
#pragma unroll
            for (int ni = 0; ni < 4; ++ni)
                acc[mi][ni] = __builtin_amdgcn_mfma_f32_16x16x32_bf16(a[mi], b[ni], acc[mi][ni], 0, 0, 0);

        if (t + 2 < nt) {
            asm volatile("s_waitcnt vmcnt(4)" ::: "memory");   // tile t+1 landed
        } else if (t + 1 < nt) {
            asm volatile("s_waitcnt vmcnt(0)" ::: "memory");   // last tile landed
        }
        if (t + 1 < nt) {
            __builtin_amdgcn_s_barrier();
            __builtin_amdgcn_sched_barrier(0);
        }
    }
    __syncthreads();  // all frag reads done before Ep overwrites LDS

    // Epilogue: 4 chunks of 32 rows x 128 cols via LDS, wave-contiguous stores.
    // acc C/D: col = lrow (+16*ni +64*wc), frag row = kg*4 + j.
#pragma unroll
    for (int mi = 0; mi < 4; ++mi) {
#pragma unroll
        for (int ni = 0; ni < 4; ++ni) {
            int c = wc * 64 + ni * 16 + lrow;
            f32x4 v = acc[mi][ni];
#pragma unroll
            for (int j = 0; j < 4; ++j) {
                float o = v[j] + bv[ni];
                if (RELU) o = fmaxf(o, 0.f);
                Ep[(wr * 16 + kg * 4 + j) * 132 + c] = o;
            }
        }
        __syncthreads();
        // wave wv stores chunk-local rows wv*8 .. wv*8+7; 2 x 256B per row
#pragma unroll
        for (int rr = 0; rr < 8; ++rr) {
            int rl = wv * 8 + rr;
            int grow = bm * 128 + (rl >> 4) * 64 + mi * 16 + (rl & 15);
            size_t base = (size_t)grow * N + bn * 128;
#pragma unroll
            for (int hh = 0; hh < 2; ++hh) {
                int c = hh * 64 + lane;
                float v = Ep[rl * 132 + c];
                if (!VOCAB || (bn * 128 + c) < N) C[base + c] = v;
            }
        }
        if (mi < 3) __syncthreads();
    }
}

extern "C" void kernel_launch(void* const* d_in, const int* in_sizes, int n_in,
                              void* d_out, int out_size, void* d_ws, size_t ws_size,
                              hipStream_t stream) {
    const int* x    = (const int*)d_in[0];
    const float* emb = (const float*)d_in[1];
    const float* pos = (const float*)d_in[2];
    const float* b1 = (const float*)d_in[3];
    const float* b2 = (const float*)d_in[4];
    const float* b3 = (const float*)d_in[5];
    const float* w2 = (const float*)d_in[6];
    const float* fb2 = (const float*)d_in[7];
    const float* w3 = (const float*)d_in[8];
    const float* fb3 = (const float*)d_in[9];
    const float* wo = (const float*)d_in[10];
    const float* fbo = (const float*)d_in[11];
    float* out = (float*)d_out;

    const int V = 50257, Vpad = 50304;  // Vpad = 393*128

    // workspace layout
    char* p = (char*)d_ws;
    u16* WO = (u16*)p;  p += (size_t)Vpad * 512 * 2;   // 51.5 MB
    u16* W2 = (u16*)p;  p += (size_t)512 * 512 * 2;
    u16* W3 = (u16*)p;  p += (size_t)512 * 512 * 2;
    u16* Abf = (u16*)p; p += (size_t)4096 * 512 * 2;   // bf16 activations [4096,512]
    float* Hb = (float*)p;                             // f32 activations [4096,512]

    // weight conversions f32 -> bf16
    cvt_bf16_kernel<<<dim3(2048), dim3(256), 0, stream>>>(wo, WO, V * 512 / 4);
    cvt_bf16_kernel<<<dim3(256), dim3(256), 0, stream>>>(w2, W2, 512 * 512 / 4);
    cvt_bf16_kernel<<<dim3(256), dim3(256), 0, stream>>>(w3, W3, 512 * 512 / 4);

    // embed + pos + leaky1 -> Abf
    embed_leaky_kernel<<<dim3(256), dim3(64), 0, stream>>>(x, emb, pos, b1, Abf);

    // fc2 + relu -> Hb
    gemm_bt_128<true, false><<<dim3(32 * 4), dim3(256), 0, stream>>>(Abf, W2, fb2, Hb, 4096, 512, 512, 32, 4);
    // leaky2 -> Abf
    leaky_bf16_kernel<<<dim3(256), dim3(64), 0, stream>>>(Hb, b2, Abf);
    // fc3 + relu -> Hb
    gemm_bt_128<true, false><<<dim3(32 * 4), dim3(256), 0, stream>>>(Abf, W3, fb3, Hb, 4096, 512, 512, 32, 4);
    // leaky3 -> Abf
    leaky_bf16_kernel<<<dim3(256), dim3(64), 0, stream>>>(Hb, b3, Abf);
    // vocab projection -> out (bn-major XCD chunks + LDS-coalesced stores)
    gemm_bt_128<false, true><<<dim3(32 * 393), dim3(256), 0, stream>>>(Abf, WO, fbo, out, 4096, V, 512, 32, 393);
}

// Round 5
// 506.542 us; speedup vs baseline: 1.4728x; 1.4728x over previous
//
#include <hip/hip_runtime.h>

typedef __attribute__((ext_vector_type(8))) short short8;
typedef __attribute__((ext_vector_type(4))) float f32x4;
typedef unsigned short u16;
typedef unsigned int u32;

#define DEVI __device__ __forceinline__

// round-to-nearest-even f32 -> bf16 bits
DEVI u16 f2bf(float f) {
    union { float f; u32 u; } v; v.f = f;
    u32 r = v.u + 0x7FFFu + ((v.u >> 16) & 1u);
    return (u16)(r >> 16);
}

// ---------------- f32 -> bf16 bulk convert (vec4) ----------------
__global__ void cvt_bf16_kernel(const float* __restrict__ in, u16* __restrict__ out, int n4) {
    int i = blockIdx.x * blockDim.x + threadIdx.x;
    int stride = gridDim.x * blockDim.x;
    for (; i < n4; i += stride) {
        float4 v = reinterpret_cast<const float4*>(in)[i];
        ushort4 o;
        o.x = f2bf(v.x); o.y = f2bf(v.y); o.z = f2bf(v.z); o.w = f2bf(v.w);
        reinterpret_cast<ushort4*>(out)[i] = o;
    }
}

// ---------------- embed + pos + leaky1 -> bf16 A ----------------
// 256 blocks x 64 threads; each block handles one b (fixed) x 64 h values.
__global__ __launch_bounds__(64)
void embed_leaky_kernel(const int* __restrict__ x, const float* __restrict__ emb,
                        const float* __restrict__ pos, const float* __restrict__ beta,
                        u16* __restrict__ Aout) {
    __shared__ int xs[128];
    int gtid = blockIdx.x * 64 + threadIdx.x;
    int b = gtid >> 9;      // constant per block
    int h = gtid & 511;
    for (int i = threadIdx.x; i < 128; i += 64) xs[i] = x[i * 32 + b];
    __syncthreads();
    float be = beta[h];
    float mem = 0.f;
    for (int t0 = 0; t0 < 128; t0 += 8) {
        float e[8];
#pragma unroll
        for (int j = 0; j < 8; ++j)
            e[j] = emb[(size_t)xs[t0 + j] * 512 + h] + pos[(t0 + j) * 512 + h];
#pragma unroll
        for (int j = 0; j < 8; ++j) {
            mem = be * mem + e[j];
            Aout[(size_t)((t0 + j) * 32 + b) * 512 + h] = f2bf(mem);
        }
    }
}

// ---------------- leaky over f32 input -> bf16 A ----------------
__global__ __launch_bounds__(64)
void leaky_bf16_kernel(const float* __restrict__ in, const float* __restrict__ beta,
                       u16* __restrict__ Aout) {
    int gtid = blockIdx.x * 64 + threadIdx.x;
    int b = gtid >> 9;
    int h = gtid & 511;
    float be = beta[h];
    float mem = 0.f;
    for (int t0 = 0; t0 < 128; t0 += 8) {
        float v[8];
#pragma unroll
        for (int j = 0; j < 8; ++j)
            v[j] = in[(size_t)((t0 + j) * 32 + b) * 512 + h];
#pragma unroll
        for (int j = 0; j < 8; ++j) {
            mem = be * mem + v[j];
            Aout[(size_t)((t0 + j) * 32 + b) * 512 + h] = f2bf(mem);
        }
    }
}

// ---------------- bf16 GEMM, C = A * B^T + bias (opt ReLU) ----------------
// A: [M, K] bf16 row-major (M % 128 == 0)
// B: [Npad, K] bf16 row-major (rows are output columns; Npad % 128 == 0)
// C: [M, N] f32
// LDS: row-major [128][64B] with XOR swizzle: the 16B slice stored at
// (row, s) holds global slice (row, s ^ ((row>>1)&3)). Global coalescing
// preserved (4 lanes/line); frag reads conflict-free (kg ^= (lrow>>1)&3).
// Single-buffer 2-barrier K-loop (round-3 proven core).
// Epilogue: LDS-transposed wave-contiguous 256B stores (NT for VOCAB).
// VOCAB: col guard to N, bijective XCD-chunked bn-major swizzle.
template<bool RELU, bool VOCAB>
__global__ __launch_bounds__(256)
void gemm_bt_128(const u16* __restrict__ A, const u16* __restrict__ B,
                 const float* __restrict__ bias, float* __restrict__ C,
                 int M, int N, int K, int tiles_m, int tiles_n) {
    __shared__ alignas(16) char smem[32 * 132 * 4];  // 16896 B, aliased
    u16* As = (u16*)smem;                 // 8 KB
    u16* Bs = (u16*)(smem + 8192);        // 8 KB
    float* Ep = (float*)smem;             // 32x132 f32 epilogue staging

    const int tid = threadIdx.x;
    int bm, bn;
    if (VOCAB) {
        // bijective XCD-chunked remap, bn-major (bm fastest): per bn, all 32
        // bm-blocks run concurrently on one XCD -> B tile fetched once (L2),
        // A (4MB) L3-resident (NT stores don't thrash L3).
        int nwg = tiles_m * tiles_n;
        int q = nwg >> 3, r = nwg & 7;
        int xcd = blockIdx.x & 7, idx = blockIdx.x >> 3;
        int wg = (xcd < r ? xcd * (q + 1) : r * (q + 1) + (xcd - r) * q) + idx;
        bn = wg / tiles_m;
        bm = wg % tiles_m;
    } else {
        bm = blockIdx.x / tiles_n;
        bn = blockIdx.x % tiles_n;
    }
    const int wv = tid >> 6;
    const int lane = tid & 63;
    const int wr = wv >> 1, wc = wv & 1;
    const int lrow = lane & 15;   // fragment row (A) / col (B) / C col
    const int kg = lane >> 4;     // k-slice (8 bf16 = 16B each)
    const int kgp = kg ^ ((lrow >> 1) & 3);  // swizzled k-slice for LDS reads

    f32x4 acc[4][4];
#pragma unroll
    for (int i = 0; i < 4; ++i)
#pragma unroll
        for (int j = 0; j < 4; ++j) acc[i][j] = (f32x4){0.f, 0.f, 0.f, 0.f};

    const size_t rowb = (size_t)K * 2;  // bytes per row
    const char* Ab = (const char*)A + (size_t)(bm * 128) * rowb;
    const char* Bb = (const char*)B + (size_t)(bn * 128) * rowb;

    // bias per lane-fragment-col, loaded up front
    float bv[4];
#pragma unroll
    for (int ni = 0; ni < 4; ++ni) {
        int col = bn * 128 + wc * 64 + ni * 16 + lrow;
        bv[ni] = (!VOCAB || col < N) ? bias[col] : 0.f;
    }

    for (int k0 = 0; k0 < K; k0 += 32) {
        int k2 = k0 << 1;
        // stage 128x32 bf16 tiles: slot s -> row = s>>2, holds global slice
        // (s&3) ^ ((row>>1)&3). 4 consecutive lanes cover one 64B line.
#pragma unroll
        for (int r = 0; r < 2; ++r) {
            int s = r * 256 + tid;
            int row = s >> 2;
            int k16g = (s & 3) ^ ((row >> 1) & 3);
            size_t goff = (size_t)row * rowb + k2 + k16g * 16;
            __builtin_amdgcn_global_load_lds(
                (const __attribute__((address_space(1))) void*)(Ab + goff),
                (__attribute__((address_space(3))) void*)((char*)As + s * 16), 16, 0, 0);
            __builtin_amdgcn_global_load_lds(
                (const __attribute__((address_space(1))) void*)(Bb + goff),
                (__attribute__((address_space(3))) void*)((char*)Bs + s * 16), 16, 0, 0);
        }
        __syncthreads();

        short8 a[4], b[4];
#pragma unroll
        for (int mi = 0; mi < 4; ++mi)
            a[mi] = *(const short8*)&As[(wr * 64 + mi * 16 + lrow) * 32 + kgp * 8];
#pragma unroll
        for (int ni = 0; ni < 4; ++ni)
            b[ni] = *(const short8*)&Bs[(wc * 64 + ni * 16 + lrow) * 32 + kgp * 8];
#pragma unroll
        for (int mi = 0; mi < 4; ++mi)
#pragma unroll
            for (int ni = 0; ni < 4; ++ni)
                acc[mi][ni] = __builtin_amdgcn_mfma_f32_16x16x32_bf16(a[mi], b[ni], acc[mi][ni], 0, 0, 0);
        __syncthreads();
    }

    // Epilogue: 4 chunks of 32 rows x 128 cols via LDS, wave-contiguous stores.
    // acc C/D: col = lrow (+16*ni +64*wc), frag row = kg*4 + j.
#pragma unroll
    for (int mi = 0; mi < 4; ++mi) {
#pragma unroll
        for (int ni = 0; ni < 4; ++ni) {
            int c = wc * 64 + ni * 16 + lrow;
            f32x4 v = acc[mi][ni];
#pragma unroll
            for (int j = 0; j < 4; ++j) {
                float o = v[j] + bv[ni];
                if (RELU) o = fmaxf(o, 0.f);
                Ep[(wr * 16 + kg * 4 + j) * 132 + c] = o;
            }
        }
        __syncthreads();
        // wave wv stores chunk-local rows wv*8 .. wv*8+7; 2 x 256B per row
#pragma unroll
        for (int rr = 0; rr < 8; ++rr) {
            int rl = wv * 8 + rr;
            int grow = bm * 128 + (rl >> 4) * 64 + mi * 16 + (rl & 15);
            size_t base = (size_t)grow * N + bn * 128;
#pragma unroll
            for (int hh = 0; hh < 2; ++hh) {
                int c = hh * 64 + lane;
                float v = Ep[rl * 132 + c];
                if (!VOCAB) {
                    C[base + c] = v;
                } else if ((bn * 128 + c) < N) {
                    __builtin_nontemporal_store(v, &C[base + c]);
                }
            }
        }
        if (mi < 3) __syncthreads();
    }
}

extern "C" void kernel_launch(void* const* d_in, const int* in_sizes, int n_in,
                              void* d_out, int out_size, void* d_ws, size_t ws_size,
                              hipStream_t stream) {
    const int* x    = (const int*)d_in[0];
    const float* emb = (const float*)d_in[1];
    const float* pos = (const float*)d_in[2];
    const float* b1 = (const float*)d_in[3];
    const float* b2 = (const float*)d_in[4];
    const float* b3 = (const float*)d_in[5];
    const float* w2 = (const float*)d_in[6];
    const float* fb2 = (const float*)d_in[7];
    const float* w3 = (const float*)d_in[8];
    const float* fb3 = (const float*)d_in[9];
    const float* wo = (const float*)d_in[10];
    const float* fbo = (const float*)d_in[11];
    float* out = (float*)d_out;

    const int V = 50257, Vpad = 50304;  // Vpad = 393*128

    // workspace layout
    char* p = (char*)d_ws;
    u16* WO = (u16*)p;  p += (size_t)Vpad * 512 * 2;   // 51.5 MB
    u16* W2 = (u16*)p;  p += (size_t)512 * 512 * 2;
    u16* W3 = (u16*)p;  p += (size_t)512 * 512 * 2;
    u16* Abf = (u16*)p; p += (size_t)4096 * 512 * 2;   // bf16 activations [4096,512]
    float* Hb = (float*)p;                             // f32 activations [4096,512]

    // weight conversions f32 -> bf16
    cvt_bf16_kernel<<<dim3(2048), dim3(256), 0, stream>>>(wo, WO, V * 512 / 4);
    cvt_bf16_kernel<<<dim3(256), dim3(256), 0, stream>>>(w2, W2, 512 * 512 / 4);
    cvt_bf16_kernel<<<dim3(256), dim3(256), 0, stream>>>(w3, W3, 512 * 512 / 4);

    // embed + pos + leaky1 -> Abf
    embed_leaky_kernel<<<dim3(256), dim3(64), 0, stream>>>(x, emb, pos, b1, Abf);

    // fc2 + relu -> Hb
    gemm_bt_128<true, false><<<dim3(32 * 4), dim3(256), 0, stream>>>(Abf, W2, fb2, Hb, 4096, 512, 512, 32, 4);
    // leaky2 -> Abf
    leaky_bf16_kernel<<<dim3(256), dim3(64), 0, stream>>>(Hb, b2, Abf);
    // fc3 + relu -> Hb
    gemm_bt_128<true, false><<<dim3(32 * 4), dim3(256), 0, stream>>>(Abf, W3, fb3, Hb, 4096, 512, 512, 32, 4);
    // leaky3 -> Abf
    leaky_bf16_kernel<<<dim3(256), dim3(64), 0, stream>>>(Hb, b3, Abf);
    // vocab projection -> out (bn-major XCD chunks + NT coalesced stores)
    gemm_bt_128<false, true><<<dim3(32 * 393), dim3(256), 0, stream>>>(Abf, WO, fbo, out, 4096, V, 512, 32, 393);
}

// Round 8
// 423.573 us; speedup vs baseline: 1.7613x; 1.1959x over previous
//
#include <hip/hip_runtime.h>

typedef __attribute__((ext_vector_type(8))) short short8;
typedef __attribute__((ext_vector_type(4))) float f32x4;
typedef unsigned short u16;
typedef unsigned int u32;

#define DEVI __device__ __forceinline__

// round-to-nearest-even f32 -> bf16 bits
DEVI u16 f2bf(float f) {
    union { float f; u32 u; } v; v.f = f;
    u32 r = v.u + 0x7FFFu + ((v.u >> 16) & 1u);
    return (u16)(r >> 16);
}

// ---------------- f32 -> bf16 bulk convert (vec4) ----------------
__global__ void cvt_bf16_kernel(const float* __restrict__ in, u16* __restrict__ out, int n4) {
    int i = blockIdx.x * blockDim.x + threadIdx.x;
    int stride = gridDim.x * blockDim.x;
    for (; i < n4; i += stride) {
        float4 v = reinterpret_cast<const float4*>(in)[i];
        ushort4 o;
        o.x = f2bf(v.x); o.y = f2bf(v.y); o.z = f2bf(v.z); o.w = f2bf(v.w);
        reinterpret_cast<ushort4*>(out)[i] = o;
    }
}

// ---------------- embed + pos + leaky1 -> bf16 A ----------------
__global__ __launch_bounds__(64)
void embed_leaky_kernel(const int* __restrict__ x, const float* __restrict__ emb,
                        const float* __restrict__ pos, const float* __restrict__ beta,
                        u16* __restrict__ Aout) {
    __shared__ int xs[128];
    int gtid = blockIdx.x * 64 + threadIdx.x;
    int b = gtid >> 9;      // constant per block
    int h = gtid & 511;
    for (int i = threadIdx.x; i < 128; i += 64) xs[i] = x[i * 32 + b];
    __syncthreads();
    float be = beta[h];
    float mem = 0.f;
    for (int t0 = 0; t0 < 128; t0 += 8) {
        float e[8];
#pragma unroll
        for (int j = 0; j < 8; ++j)
            e[j] = emb[(size_t)xs[t0 + j] * 512 + h] + pos[(t0 + j) * 512 + h];
#pragma unroll
        for (int j = 0; j < 8; ++j) {
            mem = be * mem + e[j];
            Aout[(size_t)((t0 + j) * 32 + b) * 512 + h] = f2bf(mem);
        }
    }
}

// ---------------- leaky over f32 input -> bf16 A ----------------
__global__ __launch_bounds__(64)
void leaky_bf16_kernel(const float* __restrict__ in, const float* __restrict__ beta,
                       u16* __restrict__ Aout) {
    int gtid = blockIdx.x * 64 + threadIdx.x;
    int b = gtid >> 9;
    int h = gtid & 511;
    float be = beta[h];
    float mem = 0.f;
    for (int t0 = 0; t0 < 128; t0 += 8) {
        float v[8];
#pragma unroll
        for (int j = 0; j < 8; ++j)
            v[j] = in[(size_t)((t0 + j) * 32 + b) * 512 + h];
#pragma unroll
        for (int j = 0; j < 8; ++j) {
            mem = be * mem + v[j];
            Aout[(size_t)((t0 + j) * 32 + b) * 512 + h] = f2bf(mem);
        }
    }
}

// ---------------- 128x128 bf16 GEMM (round-5 proven; used for fc2/fc3) ----
template<bool RELU>
__global__ __launch_bounds__(256)
void gemm_bt_128(const u16* __restrict__ A, const u16* __restrict__ B,
                 const float* __restrict__ bias, float* __restrict__ C,
                 int M, int N, int K, int tiles_n) {
    __shared__ alignas(16) char smem[32 * 132 * 4];
    u16* As = (u16*)smem;
    u16* Bs = (u16*)(smem + 8192);
    float* Ep = (float*)smem;

    const int tid = threadIdx.x;
    int bm = blockIdx.x / tiles_n;
    int bn = blockIdx.x % tiles_n;
    const int wv = tid >> 6;
    const int lane = tid & 63;
    const int wr = wv >> 1, wc = wv & 1;
    const int lrow = lane & 15;
    const int kg = lane >> 4;
    const int kgp = kg ^ ((lrow >> 1) & 3);

    f32x4 acc[4][4];
#pragma unroll
    for (int i = 0; i < 4; ++i)
#pragma unroll
        for (int j = 0; j < 4; ++j) acc[i][j] = (f32x4){0.f, 0.f, 0.f, 0.f};

    const size_t rowb = (size_t)K * 2;
    const char* Ab = (const char*)A + (size_t)(bm * 128) * rowb;
    const char* Bb = (const char*)B + (size_t)(bn * 128) * rowb;

    float bv[4];
#pragma unroll
    for (int ni = 0; ni < 4; ++ni)
        bv[ni] = bias[bn * 128 + wc * 64 + ni * 16 + lrow];

    for (int k0 = 0; k0 < K; k0 += 32) {
        int k2 = k0 << 1;
#pragma unroll
        for (int r = 0; r < 2; ++r) {
            int s = r * 256 + tid;
            int row = s >> 2;
            int k16g = (s & 3) ^ ((row >> 1) & 3);
            size_t goff = (size_t)row * rowb + k2 + k16g * 16;
            __builtin_amdgcn_global_load_lds(
                (const __attribute__((address_space(1))) void*)(Ab + goff),
                (__attribute__((address_space(3))) void*)((char*)As + s * 16), 16, 0, 0);
            __builtin_amdgcn_global_load_lds(
                (const __attribute__((address_space(1))) void*)(Bb + goff),
                (__attribute__((address_space(3))) void*)((char*)Bs + s * 16), 16, 0, 0);
        }
        __syncthreads();

        short8 a[4], b[4];
#pragma unroll
        for (int mi = 0; mi < 4; ++mi)
            a[mi] = *(const short8*)&As[(wr * 64 + mi * 16 + lrow) * 32 + kgp * 8];
#pragma unroll
        for (int ni = 0; ni < 4; ++ni)
            b[ni] = *(const short8*)&Bs[(wc * 64 + ni * 16 + lrow) * 32 + kgp * 8];
#pragma unroll
        for (int mi = 0; mi < 4; ++mi)
#pragma unroll
            for (int ni = 0; ni < 4; ++ni)
                acc[mi][ni] = __builtin_amdgcn_mfma_f32_16x16x32_bf16(a[mi], b[ni], acc[mi][ni], 0, 0, 0);
        __syncthreads();
    }

#pragma unroll
    for (int mi = 0; mi < 4; ++mi) {
#pragma unroll
        for (int ni = 0; ni < 4; ++ni) {
            int c = wc * 64 + ni * 16 + lrow;
            f32x4 v = acc[mi][ni];
#pragma unroll
            for (int j = 0; j < 4; ++j) {
                float o = v[j] + bv[ni];
                if (RELU) o = fmaxf(o, 0.f);
                Ep[(wr * 16 + kg * 4 + j) * 132 + c] = o;
            }
        }
        __syncthreads();
#pragma unroll
        for (int rr = 0; rr < 8; ++rr) {
            int rl = wv * 8 + rr;
            int grow = bm * 128 + (rl >> 4) * 64 + mi * 16 + (rl & 15);
            size_t base = (size_t)grow * N + bn * 128;
#pragma unroll
            for (int hh = 0; hh < 2; ++hh) {
                int c = hh * 64 + lane;
                C[base + c] = Ep[rl * 132 + c];
            }
        }
        if (mi < 3) __syncthreads();
    }
}

// ---------------- 256x256 bf16 GEMM, BK=64, 2-phase dbuf (vocab) ----------
// A: [M,K] bf16, B: [Npad,K] bf16 (rows = output cols), C: [M,N] f32 + bias.
// 512 threads = 8 waves (2 M x 4 N); per-wave out 128x64 (acc[8][4]).
// LDS per buffer: A 32KB + B 32KB, row = 64 bf16 = 8 x 16B slices,
// slice stored at s' holds global slice s'^(row&7)  (XOR involution:
// conflict-free ds_read_b128, coalesced staging sources).
// Loop: STAGE(next) issued BEFORE frag-reads+MFMA of current; 1 barrier/iter.
// Epilogue: 4 chunks of 64 rows x 256 cols via LDS [64][260], 16B/lane NT stores.
__global__ __launch_bounds__(512, 2)
void gemm_bt_256(const u16* __restrict__ A, const u16* __restrict__ B,
                 const float* __restrict__ bias, float* __restrict__ C,
                 int M, int N, int K, int tiles_m, int tiles_n) {
    extern __shared__ char smem[];   // 2 x 64KB buffers; epilogue aliases
    float* Ep = (float*)smem;        // [64][260] f32

    const int tid = threadIdx.x;
    // bijective XCD-chunked remap, bn-major (bm fastest): per bn-panel the
    // 16 bm-blocks run on one XCD -> B tile one HBM touch; A L2/L3-resident.
    int nwg = tiles_m * tiles_n;
    int q = nwg >> 3, r = nwg & 7;
    int xcd = blockIdx.x & 7, idx = blockIdx.x >> 3;
    int wg = (xcd < r ? xcd * (q + 1) : r * (q + 1) + (xcd - r) * q) + idx;
    int bn = wg / tiles_m;
    int bm = wg % tiles_m;

    const int wv = tid >> 6;
    const int lane = tid & 63;
    const int wr = wv >> 2;        // 0..1 (M half)
    const int wc = wv & 3;         // 0..3 (N quarter)
    const int lrow = lane & 15;
    const int kg = lane >> 4;      // 0..3

    f32x4 acc[8][4];
#pragma unroll
    for (int i = 0; i < 8; ++i)
#pragma unroll
        for (int j = 0; j < 4; ++j) acc[i][j] = (f32x4){0.f, 0.f, 0.f, 0.f};

    const size_t rowb = (size_t)K * 2;
    const char* Ab = (const char*)A + (size_t)(bm * 256) * rowb;
    const char* Bb = (const char*)B + (size_t)(bn * 256) * rowb;

    float bv[4];
#pragma unroll
    for (int ni = 0; ni < 4; ++ni) {
        int col = bn * 256 + wc * 64 + ni * 16 + lrow;
        bv[ni] = (col < N) ? bias[col] : 0.f;
    }

    // stage K-slab kk (64 wide) into buffer bufi: 2048 slots x 16B each for A,B
    auto STAGE = [&](int bufi, int kk) {
        char* dA = smem + bufi * 65536;
        char* dB = dA + 32768;
        int k2 = kk << 1;
#pragma unroll
        for (int i = 0; i < 4; ++i) {
            int s = i * 512 + tid;          // slot 0..2047
            int row = s >> 3;
            int sp = s & 7;
            size_t goff = (size_t)row * rowb + k2 + ((sp ^ (row & 7)) << 4);
            __builtin_amdgcn_global_load_lds(
                (const __attribute__((address_space(1))) void*)(Ab + goff),
                (__attribute__((address_space(3))) void*)(dA + s * 16), 16, 0, 0);
            __builtin_amdgcn_global_load_lds(
                (const __attribute__((address_space(1))) void*)(Bb + goff),
                (__attribute__((address_space(3))) void*)(dB + s * 16), 16, 0, 0);
        }
    };

    const int nt = K >> 6;   // BK=64 tiles
    STAGE(0, 0);
    __syncthreads();

    for (int t = 0; t < nt; ++t) {
        const int cur = t & 1;
        const char* As = smem + cur * 65536;
        const char* Bs = As + 32768;

        if (t + 1 < nt) STAGE(cur ^ 1, (t + 1) << 6);

#pragma unroll
        for (int ks = 0; ks < 2; ++ks) {
            short8 a[8], b[4];
#pragma unroll
            for (int mi = 0; mi < 8; ++mi) {
                int rr = wr * 128 + mi * 16 + lrow;
                int sl = (ks * 4 + kg) ^ (rr & 7);
                a[mi] = *(const short8*)(As + rr * 128 + sl * 16);
            }
#pragma unroll
            for (int ni = 0; ni < 4; ++ni) {
                int rr = wc * 64 + ni * 16 + lrow;
                int sl = (ks * 4 + kg) ^ (rr & 7);
                b[ni] = *(const short8*)(Bs + rr * 128 + sl * 16);
            }
#pragma unroll
            for (int mi = 0; mi < 8; ++mi)
#pragma unroll
                for (int ni = 0; ni < 4; ++ni)
                    acc[mi][ni] = __builtin_amdgcn_mfma_f32_16x16x32_bf16(a[mi], b[ni], acc[mi][ni], 0, 0, 0);
        }
        __syncthreads();   // stage(t+1) landed; buf(cur) reads done
    }

    // Epilogue: 4 chunks of 64 rows x 256 cols. Writer waves: wr == ch>>1,
    // mi in [(ch&1)*4, +4). acc row-in-chunk = m2*16 + kg*4 + j.
#pragma unroll
    for (int ch = 0; ch < 4; ++ch) {
        if (wr == (ch >> 1)) {
            int mibase = (ch & 1) * 4;
#pragma unroll
            for (int m2 = 0; m2 < 4; ++m2) {
#pragma unroll
                for (int ni = 0; ni < 4; ++ni) {
                    int c = wc * 64 + ni * 16 + lrow;
                    f32x4 v = acc[mibase + m2][ni];
#pragma unroll
                    for (int j = 0; j < 4; ++j)
                        Ep[(m2 * 16 + kg * 4 + j) * 260 + c] = v[j] + bv[ni];
                }
            }
        }
        __syncthreads();
        // all 8 waves store 8 rows each; 64 lanes x 16B = full 1KB row
#pragma unroll
        for (int rr = 0; rr < 8; ++rr) {
            int rl = wv * 8 + rr;
            int grow = bm * 256 + ch * 64 + rl;
            int gc0 = bn * 256 + lane * 4;
            f32x4 v = *(const f32x4*)&Ep[rl * 260 + lane * 4];
            if (gc0 + 3 < N) {
                __builtin_nontemporal_store(v, (f32x4*)&C[(size_t)grow * N + gc0]);
            } else {
#pragma unroll
                for (int e = 0; e < 4; ++e)
                    if (gc0 + e < N)
                        __builtin_nontemporal_store(v[e], &C[(size_t)grow * N + gc0 + e]);
            }
        }
        if (ch < 3) __syncthreads();
    }
}

extern "C" void kernel_launch(void* const* d_in, const int* in_sizes, int n_in,
                              void* d_out, int out_size, void* d_ws, size_t ws_size,
                              hipStream_t stream) {
    const int* x    = (const int*)d_in[0];
    const float* emb = (const float*)d_in[1];
    const float* pos = (const float*)d_in[2];
    const float* b1 = (const float*)d_in[3];
    const float* b2 = (const float*)d_in[4];
    const float* b3 = (const float*)d_in[5];
    const float* w2 = (const float*)d_in[6];
    const float* fb2 = (const float*)d_in[7];
    const float* w3 = (const float*)d_in[8];
    const float* fb3 = (const float*)d_in[9];
    const float* wo = (const float*)d_in[10];
    const float* fbo = (const float*)d_in[11];
    float* out = (float*)d_out;

    const int V = 50257;
    const int TN = 197;                 // 256-col tiles for vocab
    const int Vpad = TN * 256;          // 50432

    // allow >64KB dynamic LDS for the 256^2 kernel (one-time, idempotent,
    // graph-capture-safe: not a mem/sync API)
    static bool lds_cap_set = false;
    if (!lds_cap_set) {
        hipFuncSetAttribute((const void*)gemm_bt_256,
                            hipFuncAttributeMaxDynamicSharedMemorySize, 131072);
        lds_cap_set = true;
    }

    // workspace layout
    char* p = (char*)d_ws;
    u16* WO = (u16*)p;  p += (size_t)Vpad * 512 * 2;   // 51.6 MB (pad rows unused garbage)
    u16* W2 = (u16*)p;  p += (size_t)512 * 512 * 2;
    u16* W3 = (u16*)p;  p += (size_t)512 * 512 * 2;
    u16* Abf = (u16*)p; p += (size_t)4096 * 512 * 2;   // bf16 activations [4096,512]
    float* Hb = (float*)p;                             // f32 activations [4096,512]

    // weight conversions f32 -> bf16
    cvt_bf16_kernel<<<dim3(2048), dim3(256), 0, stream>>>(wo, WO, V * 512 / 4);
    cvt_bf16_kernel<<<dim3(256), dim3(256), 0, stream>>>(w2, W2, 512 * 512 / 4);
    cvt_bf16_kernel<<<dim3(256), dim3(256), 0, stream>>>(w3, W3, 512 * 512 / 4);

    // embed + pos + leaky1 -> Abf
    embed_leaky_kernel<<<dim3(256), dim3(64), 0, stream>>>(x, emb, pos, b1, Abf);

    // fc2 + relu -> Hb
    gemm_bt_128<true><<<dim3(32 * 4), dim3(256), 0, stream>>>(Abf, W2, fb2, Hb, 4096, 512, 512, 4);
    // leaky2 -> Abf
    leaky_bf16_kernel<<<dim3(256), dim3(64), 0, stream>>>(Hb, b2, Abf);
    // fc3 + relu -> Hb
    gemm_bt_128<true><<<dim3(32 * 4), dim3(256), 0, stream>>>(Abf, W3, fb3, Hb, 4096, 512, 512, 4);
    // leaky3 -> Abf
    leaky_bf16_kernel<<<dim3(256), dim3(64), 0, stream>>>(Hb, b3, Abf);
    // vocab projection -> out: 256^2 tile, 2-phase dbuf, NT stores
    gemm_bt_256<<<dim3(16 * TN), dim3(512), 131072, stream>>>(Abf, WO, fbo, out, 4096, V, 512, 16, TN);
}